// Round 11
// baseline (312.866 us; speedup 1.0000x reference)
//
#include <hip/hip_runtime.h>

#define NN 100000
#define NE 1600000
#define D 128
#define BN_EPS 1e-5f

#define NB 782        // ceil(NN / 128) buckets, bucket = dst >> 7
#define NBP 784       // padded bucket count
#define NWG_BIN 200   // workgroups in sort pass
#define CHUNK 8000    // NE / NWG_BIN, exact
#define ZOFF (NN*64)  // u32-offset of the zero row in H
#define AGG_BLOCKS 2048

typedef __attribute__((ext_vector_type(4))) _Float16 f16x4;
typedef __attribute__((ext_vector_type(4))) float f32x4;

static __device__ __forceinline__ float frelu(float x){ return x > 0.f ? x : 0.f; }

// bf16 helpers (RNE pack, cheap unpack)
static __device__ __forceinline__ unsigned short f2bf(float f){
  unsigned int u = __float_as_uint(f);
  u += 0x7fffu + ((u >> 16) & 1u);
  return (unsigned short)(u >> 16);
}
static __device__ __forceinline__ float bflo(unsigned int p){ return __uint_as_float(p << 16); }
static __device__ __forceinline__ float bfhi(unsigned int p){ return __uint_as_float(p & 0xffff0000u); }

// ---------------- sort + prep fused: blocks 0..199 sort, 200 zero, 201/202 pack W ----
__global__ __launch_bounds__(256) void k_sortprep(const int* __restrict__ ei,
                                                  int* __restrict__ wgLoc, unsigned int* __restrict__ binned,
                                                  const float* __restrict__ W1f, const float* __restrict__ W2f,
                                                  unsigned long long* __restrict__ P1, unsigned long long* __restrict__ P2,
                                                  float* __restrict__ colsumB, unsigned int* __restrict__ hw){
  __shared__ int hist[NBP];
  __shared__ int lofs[NBP];
  __shared__ int fill[NBP];
  __shared__ int tsum[256];
  int t = threadIdx.x, w = blockIdx.x;

  if (w >= NWG_BIN){
    if (w == NWG_BIN){
      for (int i = t; i < 4096; i += 256) colsumB[i] = 0.f;  // 2 regions x 8 banks x 256
      if (t < 64) hw[ZOFF + t] = 0u;                          // zero sentinel row
    } else {
      const float* W = (w == NWG_BIN + 2) ? W2f : W1f;
      unsigned long long* P = (w == NWG_BIN + 2) ? P2 : P1;
      for (int i = 0; i < 16; i++){
        int s = t*16 + i;
        int l = s & 63, kt = (s >> 6) & 7, nt = s >> 9;
        int krow = kt*16 + ((l >> 4) << 2);
        int col = nt*16 + (l & 15);
        f16x4 v;
        #pragma unroll
        for (int j = 0; j < 4; j++) v[j] = (_Float16)W[(krow + j)*D + col];
        P[s] = __builtin_bit_cast(unsigned long long, v);
      }
    }
    return;
  }

  // ---- per-WG local counting sort into own region ----
  for (int i = t; i < NBP; i += 256){ hist[i] = 0; fill[i] = 0; }
  __syncthreads();

  int base = w*CHUNK;
  for (int e = base + t; e < base + CHUNK; e += 256)
    atomicAdd(&hist[ei[NE + e] >> 7], 1);
  __syncthreads();

  int b0 = t*4;
  int h0 = 0, h1 = 0, h2 = 0, h3 = 0, s = 0;
  if (b0 < NBP){
    h0 = hist[b0]; h1 = hist[b0+1]; h2 = hist[b0+2]; h3 = hist[b0+3];
    s = h0 + h1 + h2 + h3;
  }
  tsum[t] = s; __syncthreads();
  for (int off = 1; off < 256; off <<= 1){
    int u = (t >= off) ? tsum[t - off] : 0;
    __syncthreads(); tsum[t] += u; __syncthreads();
  }
  if (b0 < NBP){
    int ex = tsum[t] - s;
    lofs[b0] = ex; lofs[b0+1] = ex + h0; lofs[b0+2] = ex + h0 + h1; lofs[b0+3] = ex + h0 + h1 + h2;
  }
  __syncthreads();

  for (int i = t; i < NB + 1; i += 256) wgLoc[w*NBP + i] = lofs[i];

  for (int e = base + t; e < base + CHUNK; e += 256){
    int sc = ei[e], d = ei[NE + e];
    int b = d >> 7;
    int r = atomicAdd(&fill[b], 1);
    binned[base + lofs[b] + r] = ((unsigned)sc << 7) | (unsigned)(d & 127);
  }
}

// ---- per-bucket node build (wave-cooperative fragments) -> cnt/rowStart/dinv/colIdx ----
// s0 = sum_w wgLoc[w][b]. Fragment f of bucket b processed by wave f&3 with
// coalesced 64-lane reads. List per node: [self][edges...][ZOFF pads], x8.
__global__ __launch_bounds__(256) void kb_node2(const unsigned int* __restrict__ binned,
                                                const int* __restrict__ wgLoc,
                                                int* __restrict__ cnt, int* __restrict__ rowStart,
                                                float* __restrict__ dinv, int* __restrict__ colIdx){
  __shared__ int ncnt[128], roff[128], nfill[128];
  __shared__ int psum[256];
  int b = blockIdx.x, t = threadIdx.x;
  int wv = t >> 6, lane = t & 63;

  psum[t] = (t < NWG_BIN) ? wgLoc[t*NBP + b] : 0;
  if (t < 128){ ncnt[t] = 0; nfill[t] = 0; }
  __syncthreads();
  for (int off = 128; off > 0; off >>= 1){
    if (t < off) psum[t] += psum[t + off];
    __syncthreads();
  }
  int s0 = psum[0];

  int node0 = b << 7;
  int nNodes = min(128, NN - node0);

  // phase 1: per-node counts (wave per fragment, coalesced binned reads)
  for (int f = wv; f < NWG_BIN; f += 4){
    int fb = wgLoc[f*NBP + b], fe = wgLoc[f*NBP + b + 1];
    int base = f*CHUNK + fb, len = fe - fb;
    for (int o = lane; o < len; o += 64)
      atomicAdd(&ncnt[binned[base + o] & 127], 1);
  }
  __syncthreads();
  if (t < 128) roff[t] = ncnt[t];
  __syncthreads();
  for (int off = 1; off < 128; off <<= 1){
    int u = (t >= off && t < 128) ? roff[t - off] : 0;
    __syncthreads(); if (t < 128) roff[t] += u; __syncthreads();
  }
  if (t < nNodes){
    int n = ncnt[t];
    int node = node0 + t;
    int padBase = s0 + (roff[t] - n) + 8*node;
    rowStart[node] = padBase;
    cnt[node] = n;
    dinv[node] = rsqrtf((float)(n + 1));
    colIdx[padBase] = node << 6;                 // self entry
    int nTot = n + 1;
    int nP = (nTot + 7) & ~7;
    for (int i = nTot; i < nP; i++) colIdx[padBase + i] = ZOFF;  // zero-row pads
  }
  __syncthreads();
  // phase 2: placement (wave per fragment)
  for (int f = wv; f < NWG_BIN; f += 4){
    int fb = wgLoc[f*NBP + b], fe = wgLoc[f*NBP + b + 1];
    int base = f*CHUNK + fb, len = fe - fb;
    for (int o = lane; o < len; o += 64){
      unsigned int ed = binned[base + o];
      int l = ed & 127;
      int r = atomicAdd(&nfill[l], 1);
      colIdx[s0 + (roff[l] - ncnt[l]) + 8*(node0 + l) + 1 + r] = (int)((ed >> 7) << 6);  // src*64
    }
  }
}

// ---------------- GEMM layer 1: H[r] = bf16( dinv[r] * (X[r] @ W) ), f32 input ----
__global__ __launch_bounds__(256) void k_gemm1(const float* __restrict__ X,
                                               const unsigned long long* __restrict__ Wpk,
                                               const float* __restrict__ dinv,
                                               unsigned short* __restrict__ H){
  int tid = threadIdx.x, lane = tid & 63;
  int row0 = blockIdx.x*64 + (tid >> 6)*16;
  int arow = row0 + (lane & 15); if (arow >= NN) arow = NN - 1;
  int kg = lane >> 4;  // 0..3

  const float4* X4 = (const float4*)X;
  f16x4 a[8];
  #pragma unroll
  for (int kt = 0; kt < 8; kt++){
    float4 xv = X4[(size_t)arow*32 + kt*4 + kg];
    f16x4 av;
    av[0] = (_Float16)xv.x; av[1] = (_Float16)xv.y;
    av[2] = (_Float16)xv.z; av[3] = (_Float16)xv.w;
    a[kt] = av;
  }

  f32x4 acc[8];
  #pragma unroll
  for (int nt = 0; nt < 8; nt++){ acc[nt][0] = 0.f; acc[nt][1] = 0.f; acc[nt][2] = 0.f; acc[nt][3] = 0.f; }

  #pragma unroll
  for (int kt = 0; kt < 8; kt++){
    #pragma unroll
    for (int nt = 0; nt < 8; nt++){
      f16x4 bfr = __builtin_bit_cast(f16x4, Wpk[(nt*8 + kt)*64 + lane]);
      acc[nt] = __builtin_amdgcn_mfma_f32_16x16x16f16(a[kt], bfr, acc[nt], 0, 0, 0);
    }
  }

  int rbase = row0 + kg*4;
  float4 dv = *(const float4*)&dinv[rbase];
  #pragma unroll
  for (int r = 0; r < 4; r++){
    int row = rbase + r;
    if (row < NN){
      float sc = (r == 0) ? dv.x : (r == 1) ? dv.y : (r == 2) ? dv.z : dv.w;
      #pragma unroll
      for (int nt = 0; nt < 8; nt++)
        H[(size_t)row*D + nt*16 + (lane & 15)] = f2bf(acc[nt][r]*sc);
    }
  }
}

// ---------------- GEMM layer 2: input = relu(gb*aggb + bb), gb/bb inline ---------
__global__ __launch_bounds__(256) void k_gemm2(const unsigned int* __restrict__ A,
                                               const float* __restrict__ colsum,
                                               const float* __restrict__ gamma, const float* __restrict__ beta,
                                               const unsigned long long* __restrict__ Wpk,
                                               const float* __restrict__ dinv,
                                               unsigned short* __restrict__ H){
  __shared__ float gbL[128], bbL[128];
  int tid = threadIdx.x, lane = tid & 63;
  if (tid < 128){
    float s = 0.f, q = 0.f;
    #pragma unroll
    for (int k = 0; k < 8; k++){ s += colsum[k*256 + tid]; q += colsum[k*256 + 128 + tid]; }
    float mu = s * (1.f / NN);
    float var = q * (1.f / NN) - mu*mu;
    float g = gamma[tid] * rsqrtf(var + BN_EPS);
    gbL[tid] = g;
    bbL[tid] = beta[tid] - mu*g;
  }
  __syncthreads();

  int row0 = blockIdx.x*64 + (tid >> 6)*16;
  int arow = row0 + (lane & 15); if (arow >= NN) arow = NN - 1;
  int kg = lane >> 4;  // 0..3

  const uint2* A2 = (const uint2*)A;
  f16x4 a[8];
  #pragma unroll
  for (int kt = 0; kt < 8; kt++){
    uint2 v = A2[(size_t)arow*32 + kt*4 + kg];
    int c0 = kt*16 + kg*4;
    float4 g = *(const float4*)&gbL[c0];
    float4 bo = *(const float4*)&bbL[c0];
    f16x4 av;
    av[0] = (_Float16)frelu(bflo(v.x)*g.x + bo.x);
    av[1] = (_Float16)frelu(bfhi(v.x)*g.y + bo.y);
    av[2] = (_Float16)frelu(bflo(v.y)*g.z + bo.z);
    av[3] = (_Float16)frelu(bfhi(v.y)*g.w + bo.w);
    a[kt] = av;
  }

  f32x4 acc[8];
  #pragma unroll
  for (int nt = 0; nt < 8; nt++){ acc[nt][0] = 0.f; acc[nt][1] = 0.f; acc[nt][2] = 0.f; acc[nt][3] = 0.f; }

  #pragma unroll
  for (int kt = 0; kt < 8; kt++){
    #pragma unroll
    for (int nt = 0; nt < 8; nt++){
      f16x4 bfr = __builtin_bit_cast(f16x4, Wpk[(nt*8 + kt)*64 + lane]);
      acc[nt] = __builtin_amdgcn_mfma_f32_16x16x16f16(a[kt], bfr, acc[nt], 0, 0, 0);
    }
  }

  int rbase = row0 + kg*4;
  float4 dv = *(const float4*)&dinv[rbase];
  #pragma unroll
  for (int r = 0; r < 4; r++){
    int row = rbase + r;
    if (row < NN){
      float sc = (r == 0) ? dv.x : (r == 1) ? dv.y : (r == 2) ? dv.z : dv.w;
      #pragma unroll
      for (int nt = 0; nt < 8; nt++)
        H[(size_t)row*D + nt*16 + (lane & 15)] = f2bf(acc[nt][r]*sc);
    }
  }
}

// ---------------- aggregate layer 1: gather + fused BN column sums ---------------
__global__ __launch_bounds__(256) void k_agg1(const unsigned int* __restrict__ Hp,
                                              const float* __restrict__ dinv,
                                              const int* __restrict__ rowStart,
                                              const int* __restrict__ cnt,
                                              const int* __restrict__ colIdx,
                                              unsigned int* __restrict__ outb,
                                              float* __restrict__ colsumR){
  __shared__ float lsum[128], lsq[128];
  int tid = threadIdx.x;
  if (tid < 128){ lsum[tid] = 0.f; lsq[tid] = 0.f; }
  __syncthreads();

  int lane = tid & 63, wv = tid >> 6;
  float cs0 = 0.f, cs1 = 0.f, cq0 = 0.f, cq1 = 0.f;

  for (int g = blockIdx.x; g < NN/4; g += gridDim.x){
    int node = g*4 + wv;
    int beg = __builtin_amdgcn_readfirstlane(rowStart[node]);
    int n   = __builtin_amdgcn_readfirstlane(cnt[node]);
    int nP  = (n + 8) & ~7;            // (n+1 entries incl. self) padded to x8
    const int* cp = colIdx + beg;

    float2 a0 = make_float2(0.f, 0.f), a1 = a0, a2 = a0, a3 = a0;
    float2 a4 = a0, a5 = a0, a6 = a0, a7 = a0;
    for (int j = 0; j < nP; j += 8){
      int i0 = cp[j  ], i1 = cp[j+1], i2 = cp[j+2], i3 = cp[j+3];
      int i4 = cp[j+4], i5 = cp[j+5], i6 = cp[j+6], i7 = cp[j+7];
      unsigned int v0 = Hp[i0 + lane];
      unsigned int v1 = Hp[i1 + lane];
      unsigned int v2 = Hp[i2 + lane];
      unsigned int v3 = Hp[i3 + lane];
      unsigned int v4 = Hp[i4 + lane];
      unsigned int v5 = Hp[i5 + lane];
      unsigned int v6 = Hp[i6 + lane];
      unsigned int v7 = Hp[i7 + lane];
      a0.x += bflo(v0); a0.y += bfhi(v0);
      a1.x += bflo(v1); a1.y += bfhi(v1);
      a2.x += bflo(v2); a2.y += bfhi(v2);
      a3.x += bflo(v3); a3.y += bfhi(v3);
      a4.x += bflo(v4); a4.y += bfhi(v4);
      a5.x += bflo(v5); a5.y += bfhi(v5);
      a6.x += bflo(v6); a6.y += bfhi(v6);
      a7.x += bflo(v7); a7.y += bfhi(v7);
    }

    float sx = ((a0.x + a1.x) + (a2.x + a3.x)) + ((a4.x + a5.x) + (a6.x + a7.x));
    float sy = ((a0.y + a1.y) + (a2.y + a3.y)) + ((a4.y + a5.y) + (a6.y + a7.y));
    float di = dinv[node];
    unsigned int pk = (unsigned int)f2bf(di*sx) | ((unsigned int)f2bf(di*sy) << 16);
    outb[node*64 + lane] = pk;

    float r0 = bflo(pk), r1 = bfhi(pk);
    cs0 += r0; cq0 += r0*r0;
    cs1 += r1; cq1 += r1*r1;
  }

  atomicAdd(&lsum[lane*2    ], cs0); atomicAdd(&lsq[lane*2    ], cq0);
  atomicAdd(&lsum[lane*2 + 1], cs1); atomicAdd(&lsq[lane*2 + 1], cq1);
  __syncthreads();
  int bank = (blockIdx.x & 7)*256;
  if (tid < 128) atomicAdd(&colsumR[bank + tid], lsum[tid]);
  else if (tid < 256) atomicAdd(&colsumR[bank + tid], lsq[tid - 128]);
}

// ---------------- aggregate layer 2: + emits o1 from old aggb under the fetch wall ----
// Reads node's layer-1 aggb, applies inline gb/bb (colsum0) + ReLU -> o1 (f32),
// gathers layer-2 H, overwrites aggb, accumulates colsum1. o1 write hides under
// the L3-fetch-bound gather (HBM write path idle in k_agg).
__global__ __launch_bounds__(256) void k_agg2(const unsigned int* __restrict__ Hp,
                                              const float* __restrict__ dinv,
                                              const int* __restrict__ rowStart,
                                              const int* __restrict__ cnt,
                                              const int* __restrict__ colIdx,
                                              unsigned int* __restrict__ aggb,
                                              const float* __restrict__ colsum0,
                                              const float* __restrict__ gamma, const float* __restrict__ beta,
                                              float* __restrict__ o1,
                                              float* __restrict__ colsumR){
  __shared__ float lsum[128], lsq[128];
  __shared__ float gbL[128], bbL[128];
  int tid = threadIdx.x;
  if (tid < 128){
    lsum[tid] = 0.f; lsq[tid] = 0.f;
    float s = 0.f, q = 0.f;
    #pragma unroll
    for (int k = 0; k < 8; k++){ s += colsum0[k*256 + tid]; q += colsum0[k*256 + 128 + tid]; }
    float mu = s * (1.f / NN);
    float var = q * (1.f / NN) - mu*mu;
    float g = gamma[tid] * rsqrtf(var + BN_EPS);
    gbL[tid] = g;
    bbL[tid] = beta[tid] - mu*g;
  }
  __syncthreads();

  int lane = tid & 63, wv = tid >> 6;
  float2 gC = ((const float2*)gbL)[lane];
  float2 bC = ((const float2*)bbL)[lane];
  float cs0 = 0.f, cs1 = 0.f, cq0 = 0.f, cq1 = 0.f;

  for (int g = blockIdx.x; g < NN/4; g += gridDim.x){
    int node = g*4 + wv;
    int beg = __builtin_amdgcn_readfirstlane(rowStart[node]);
    int n   = __builtin_amdgcn_readfirstlane(cnt[node]);
    int nP  = (n + 8) & ~7;
    const int* cp = colIdx + beg;

    // o1 from layer-1 aggb (read-before-overwrite, same wave owns the node)
    unsigned int old = aggb[node*64 + lane];
    ((float2*)o1)[node*64 + lane] = make_float2(frelu(bflo(old)*gC.x + bC.x),
                                                frelu(bfhi(old)*gC.y + bC.y));

    float2 a0 = make_float2(0.f, 0.f), a1 = a0, a2 = a0, a3 = a0;
    float2 a4 = a0, a5 = a0, a6 = a0, a7 = a0;
    for (int j = 0; j < nP; j += 8){
      int i0 = cp[j  ], i1 = cp[j+1], i2 = cp[j+2], i3 = cp[j+3];
      int i4 = cp[j+4], i5 = cp[j+5], i6 = cp[j+6], i7 = cp[j+7];
      unsigned int v0 = Hp[i0 + lane];
      unsigned int v1 = Hp[i1 + lane];
      unsigned int v2 = Hp[i2 + lane];
      unsigned int v3 = Hp[i3 + lane];
      unsigned int v4 = Hp[i4 + lane];
      unsigned int v5 = Hp[i5 + lane];
      unsigned int v6 = Hp[i6 + lane];
      unsigned int v7 = Hp[i7 + lane];
      a0.x += bflo(v0); a0.y += bfhi(v0);
      a1.x += bflo(v1); a1.y += bfhi(v1);
      a2.x += bflo(v2); a2.y += bfhi(v2);
      a3.x += bflo(v3); a3.y += bfhi(v3);
      a4.x += bflo(v4); a4.y += bfhi(v4);
      a5.x += bflo(v5); a5.y += bfhi(v5);
      a6.x += bflo(v6); a6.y += bfhi(v6);
      a7.x += bflo(v7); a7.y += bfhi(v7);
    }

    float sx = ((a0.x + a1.x) + (a2.x + a3.x)) + ((a4.x + a5.x) + (a6.x + a7.x));
    float sy = ((a0.y + a1.y) + (a2.y + a3.y)) + ((a4.y + a5.y) + (a6.y + a7.y));
    float di = dinv[node];
    unsigned int pk = (unsigned int)f2bf(di*sx) | ((unsigned int)f2bf(di*sy) << 16);
    aggb[node*64 + lane] = pk;

    float r0 = bflo(pk), r1 = bfhi(pk);
    cs0 += r0; cq0 += r0*r0;
    cs1 += r1; cq1 += r1*r1;
  }

  atomicAdd(&lsum[lane*2    ], cs0); atomicAdd(&lsq[lane*2    ], cq0);
  atomicAdd(&lsum[lane*2 + 1], cs1); atomicAdd(&lsq[lane*2 + 1], cq1);
  __syncthreads();
  int bank = (blockIdx.x & 7)*256;
  if (tid < 128) atomicAdd(&colsumR[bank + tid], lsum[tid]);
  else if (tid < 256) atomicAdd(&colsumR[bank + tid], lsq[tid - 128]);
}

// ---------------- BN apply + ReLU (layer 2): gb/bb inline, grid-stride -----------
__global__ __launch_bounds__(256) void k_bnapply(const unsigned int* __restrict__ A,
                                                 const float* __restrict__ colsum,
                                                 const float* __restrict__ gamma, const float* __restrict__ beta,
                                                 float* __restrict__ out){
  __shared__ float gbL[128], bbL[128];
  int tid = threadIdx.x;
  if (tid < 128){
    float s = 0.f, q = 0.f;
    #pragma unroll
    for (int k = 0; k < 8; k++){ s += colsum[k*256 + tid]; q += colsum[k*256 + 128 + tid]; }
    float mu = s * (1.f / NN);
    float var = q * (1.f / NN) - mu*mu;
    float g = gamma[tid] * rsqrtf(var + BN_EPS);
    gbL[tid] = g;
    bbL[tid] = beta[tid] - mu*g;
  }
  __syncthreads();

  for (int idx = blockIdx.x*256 + tid; idx < NN*64; idx += gridDim.x*256){
    unsigned int v = A[idx];
    int c2 = idx & 63;
    float2 g = ((const float2*)gbL)[c2];
    float2 b = ((const float2*)bbL)[c2];
    float lo = frelu(bflo(v)*g.x + b.x);
    float hi = frelu(bfhi(v)*g.y + b.y);
    ((float2*)out)[idx] = make_float2(lo, hi);
  }
}

extern "C" void kernel_launch(void* const* d_in, const int* in_sizes, int n_in,
                              void* d_out, int out_size, void* d_ws, size_t ws_size,
                              hipStream_t stream){
  const float* x   = (const float*)d_in[0];
  const int*   ei  = (const int*)d_in[1];   // [2][NE], row0 = src, row1 = dst
  const float* W1  = (const float*)d_in[2];
  const float* g1  = (const float*)d_in[4];
  const float* be1 = (const float*)d_in[5];
  const float* W2  = (const float*)d_in[6];
  const float* g2  = (const float*)d_in[8];
  const float* be2 = (const float*)d_in[9];
  // b1/b2 cancel exactly inside BatchNorm (agg+b - mean(agg+b)) -> skipped.

  float* out = (float*)d_out;
  float* o1 = out;
  float* o2 = out + (size_t)NN*D;

  char* ws = (char*)d_ws;
  int*   cnt         = (int*)(ws + 0);           // 400000 B
  int*   rowStart    = (int*)(ws + 400384);      // 400000 B (padded starts)
  float* dinv        = (float*)(ws + 800768);    // 400000 B
  float* colsumB     = (float*)(ws + 1201152);   // 16384 B (2 regions x 8 banks x 256)
  int*   wgLoc       = (int*)(ws + 1217536);     // 627200 B
  unsigned long long* Wpk1 = (unsigned long long*)(ws + 1844736);  // 32768 B
  unsigned long long* Wpk2 = (unsigned long long*)(ws + 1877504);  // 32768 B
  int*   colIdx      = (int*)(ws + 1910272);     // (NE + 8*NN + 256)*4 = 9601024 B
  unsigned int* binned = (unsigned int*)(ws + 11511296);  // 6.4 MB
  unsigned int* aggb = (unsigned int*)(ws + 17911296);    // 25.6 MB (bf16 agg)
  unsigned short* h  = (unsigned short*)(ws + 43511296);  // 25.6 MB + 256 B zero row
  // total ~69.1 MB of ws

  float* colsum0 = colsumB;          // layer-1 region
  float* colsum1 = colsumB + 2048;   // layer-2 region

  // ---- build: sort+prep fused, then wave-cooperative node build ----
  k_sortprep<<<NWG_BIN + 3, 256, 0, stream>>>(ei, wgLoc, binned, W1, W2, Wpk1, Wpk2, colsumB, (unsigned int*)h);
  kb_node2  <<<NB, 256, 0, stream>>>(binned, wgLoc, cnt, rowStart, dinv, colIdx);

  // ---- layer 1 ----
  k_gemm1   <<<(NN + 63)/64, 256, 0, stream>>>(x, Wpk1, dinv, h);
  k_agg1    <<<AGG_BLOCKS, 256, 0, stream>>>((const unsigned int*)h, dinv, rowStart, cnt, colIdx, aggb, colsum0);

  // ---- layer 2 (gemm: BN inline; agg2: emits o1 + overwrites aggb) ----
  k_gemm2   <<<(NN + 63)/64, 256, 0, stream>>>(aggb, colsum0, g1, be1, Wpk2, dinv, h);
  k_agg2    <<<AGG_BLOCKS, 256, 0, stream>>>((const unsigned int*)h, dinv, rowStart, cnt, colIdx, aggb,
                                             colsum0, g1, be1, o1, colsum1);
  k_bnapply <<<AGG_BLOCKS, 256, 0, stream>>>(aggb, colsum1, g2, be2, o2);
}

// Round 12
// 266.118 us; speedup vs baseline: 1.1757x; 1.1757x over previous
//
#include <hip/hip_runtime.h>

#define NN 100000
#define NE 1600000
#define D 128
#define BN_EPS 1e-5f

#define NB 782        // ceil(NN / 128) buckets, bucket = dst >> 7
#define NBP 784       // padded bucket count
#define NWG_BIN 200   // workgroups in sort pass
#define CHUNK 8000    // NE / NWG_BIN, exact
#define ZOFF (NN*64)  // u32-offset of the zero row in H
#define AGG_BLOCKS 2048

typedef __attribute__((ext_vector_type(4))) _Float16 f16x4;
typedef __attribute__((ext_vector_type(4))) float f32x4;

static __device__ __forceinline__ float frelu(float x){ return x > 0.f ? x : 0.f; }

// bf16 helpers (RNE pack, cheap unpack)
static __device__ __forceinline__ unsigned short f2bf(float f){
  unsigned int u = __float_as_uint(f);
  u += 0x7fffu + ((u >> 16) & 1u);
  return (unsigned short)(u >> 16);
}
static __device__ __forceinline__ float bflo(unsigned int p){ return __uint_as_float(p << 16); }
static __device__ __forceinline__ float bfhi(unsigned int p){ return __uint_as_float(p & 0xffff0000u); }

// ---------------- sort + prep fused: blocks 0..199 sort, 200 zero, 201/202 pack W ----
__global__ __launch_bounds__(256) void k_sortprep(const int* __restrict__ ei,
                                                  int* __restrict__ wgLoc, unsigned int* __restrict__ binned,
                                                  const float* __restrict__ W1f, const float* __restrict__ W2f,
                                                  unsigned long long* __restrict__ P1, unsigned long long* __restrict__ P2,
                                                  float* __restrict__ colsumB, unsigned int* __restrict__ hw){
  __shared__ int hist[NBP];
  __shared__ int lofs[NBP];
  __shared__ int fill[NBP];
  __shared__ int tsum[256];
  int t = threadIdx.x, w = blockIdx.x;

  if (w >= NWG_BIN){
    if (w == NWG_BIN){
      for (int i = t; i < 4096; i += 256) colsumB[i] = 0.f;  // 2 regions x 8 banks x 256
      if (t < 64) hw[ZOFF + t] = 0u;                          // zero sentinel row
    } else {
      const float* W = (w == NWG_BIN + 2) ? W2f : W1f;
      unsigned long long* P = (w == NWG_BIN + 2) ? P2 : P1;
      for (int i = 0; i < 16; i++){
        int s = t*16 + i;
        int l = s & 63, kt = (s >> 6) & 7, nt = s >> 9;
        int krow = kt*16 + ((l >> 4) << 2);
        int col = nt*16 + (l & 15);
        f16x4 v;
        #pragma unroll
        for (int j = 0; j < 4; j++) v[j] = (_Float16)W[(krow + j)*D + col];
        P[s] = __builtin_bit_cast(unsigned long long, v);
      }
    }
    return;
  }

  // ---- per-WG local counting sort into own region ----
  for (int i = t; i < NBP; i += 256){ hist[i] = 0; fill[i] = 0; }
  __syncthreads();

  int base = w*CHUNK;
  for (int e = base + t; e < base + CHUNK; e += 256)
    atomicAdd(&hist[ei[NE + e] >> 7], 1);
  __syncthreads();

  int b0 = t*4;
  int h0 = 0, h1 = 0, h2 = 0, h3 = 0, s = 0;
  if (b0 < NBP){
    h0 = hist[b0]; h1 = hist[b0+1]; h2 = hist[b0+2]; h3 = hist[b0+3];
    s = h0 + h1 + h2 + h3;
  }
  tsum[t] = s; __syncthreads();
  for (int off = 1; off < 256; off <<= 1){
    int u = (t >= off) ? tsum[t - off] : 0;
    __syncthreads(); tsum[t] += u; __syncthreads();
  }
  if (b0 < NBP){
    int ex = tsum[t] - s;
    lofs[b0] = ex; lofs[b0+1] = ex + h0; lofs[b0+2] = ex + h0 + h1; lofs[b0+3] = ex + h0 + h1 + h2;
  }
  __syncthreads();

  for (int i = t; i < NB + 1; i += 256) wgLoc[w*NBP + i] = lofs[i];

  for (int e = base + t; e < base + CHUNK; e += 256){
    int sc = ei[e], d = ei[NE + e];
    int b = d >> 7;
    int r = atomicAdd(&fill[b], 1);
    binned[base + lofs[b] + r] = ((unsigned)sc << 7) | (unsigned)(d & 127);
  }
}

// ---- per-bucket node build -> cnt/rowStart/dinv/colIdx ---------------------------
// s0 = sum_w wgLoc[w][b]  (each wgLoc row is a per-WG exclusive scan => column sum
// is the global bucket prefix). List per node: [self][edges...][ZOFF pads], x8.
__global__ __launch_bounds__(256) void kb_node2(const unsigned int* __restrict__ binned,
                                                const int* __restrict__ wgLoc,
                                                int* __restrict__ cnt, int* __restrict__ rowStart,
                                                float* __restrict__ dinv, int* __restrict__ colIdx){
  __shared__ int ncnt[128], roff[128], nfill[128];
  __shared__ int psum[256];
  int b = blockIdx.x, t = threadIdx.x;

  psum[t] = (t < NWG_BIN) ? wgLoc[t*NBP + b] : 0;
  if (t < 128){ ncnt[t] = 0; nfill[t] = 0; }
  __syncthreads();
  for (int off = 128; off > 0; off >>= 1){
    if (t < off) psum[t] += psum[t + off];
    __syncthreads();
  }
  int s0 = psum[0];

  int node0 = b << 7;
  int nNodes = min(128, NN - node0);

  int fb = 0, fe = 0;
  if (t < NWG_BIN){
    fb = t*CHUNK + wgLoc[t*NBP + b];
    fe = t*CHUNK + wgLoc[t*NBP + b + 1];
    for (int e = fb; e < fe; e++)
      atomicAdd(&ncnt[binned[e] & 127], 1);
  }
  __syncthreads();
  if (t < 128) roff[t] = ncnt[t];
  __syncthreads();
  for (int off = 1; off < 128; off <<= 1){
    int u = (t >= off && t < 128) ? roff[t - off] : 0;
    __syncthreads(); if (t < 128) roff[t] += u; __syncthreads();
  }
  if (t < nNodes){
    int n = ncnt[t];
    int node = node0 + t;
    int padBase = s0 + (roff[t] - n) + 8*node;
    rowStart[node] = padBase;
    cnt[node] = n;
    dinv[node] = rsqrtf((float)(n + 1));
    colIdx[padBase] = node << 6;                 // self entry
    int nTot = n + 1;
    int nP = (nTot + 7) & ~7;
    for (int i = nTot; i < nP; i++) colIdx[padBase + i] = ZOFF;  // zero-row pads
  }
  __syncthreads();
  if (t < NWG_BIN){
    for (int e = fb; e < fe; e++){
      unsigned int ed = binned[e];
      int l = ed & 127;
      int r = atomicAdd(&nfill[l], 1);
      colIdx[s0 + (roff[l] - ncnt[l]) + 8*(node0 + l) + 1 + r] = (int)((ed >> 7) << 6);  // src*64
    }
  }
}

// ---------------- GEMM layer 1: H[r] = bf16( dinv[r] * (X[r] @ W) ), f32 input ----
__global__ __launch_bounds__(256) void k_gemm1(const float* __restrict__ X,
                                               const unsigned long long* __restrict__ Wpk,
                                               const float* __restrict__ dinv,
                                               unsigned short* __restrict__ H){
  int tid = threadIdx.x, lane = tid & 63;
  int row0 = blockIdx.x*64 + (tid >> 6)*16;
  int arow = row0 + (lane & 15); if (arow >= NN) arow = NN - 1;
  int kg = lane >> 4;  // 0..3

  const float4* X4 = (const float4*)X;
  f16x4 a[8];
  #pragma unroll
  for (int kt = 0; kt < 8; kt++){
    float4 xv = X4[(size_t)arow*32 + kt*4 + kg];
    f16x4 av;
    av[0] = (_Float16)xv.x; av[1] = (_Float16)xv.y;
    av[2] = (_Float16)xv.z; av[3] = (_Float16)xv.w;
    a[kt] = av;
  }

  f32x4 acc[8];
  #pragma unroll
  for (int nt = 0; nt < 8; nt++){ acc[nt][0] = 0.f; acc[nt][1] = 0.f; acc[nt][2] = 0.f; acc[nt][3] = 0.f; }

  #pragma unroll
  for (int kt = 0; kt < 8; kt++){
    #pragma unroll
    for (int nt = 0; nt < 8; nt++){
      f16x4 bfr = __builtin_bit_cast(f16x4, Wpk[(nt*8 + kt)*64 + lane]);
      acc[nt] = __builtin_amdgcn_mfma_f32_16x16x16f16(a[kt], bfr, acc[nt], 0, 0, 0);
    }
  }

  int rbase = row0 + kg*4;
  float4 dv = *(const float4*)&dinv[rbase];
  #pragma unroll
  for (int r = 0; r < 4; r++){
    int row = rbase + r;
    if (row < NN){
      float sc = (r == 0) ? dv.x : (r == 1) ? dv.y : (r == 2) ? dv.z : dv.w;
      #pragma unroll
      for (int nt = 0; nt < 8; nt++)
        H[(size_t)row*D + nt*16 + (lane & 15)] = f2bf(acc[nt][r]*sc);
    }
  }
}

// ---------------- GEMM layer 2: gb/bb computed inline from colsum region ---------
__global__ __launch_bounds__(256) void k_gemm2(const unsigned int* __restrict__ A,
                                               const float* __restrict__ colsum,
                                               const float* __restrict__ gamma, const float* __restrict__ beta,
                                               const unsigned long long* __restrict__ Wpk,
                                               const float* __restrict__ dinv,
                                               unsigned short* __restrict__ H,
                                               float* __restrict__ o1){
  __shared__ float gbL[128], bbL[128];
  int tid = threadIdx.x, lane = tid & 63;
  if (tid < 128){
    float s = 0.f, q = 0.f;
    #pragma unroll
    for (int k = 0; k < 8; k++){ s += colsum[k*256 + tid]; q += colsum[k*256 + 128 + tid]; }
    float mu = s * (1.f / NN);
    float var = q * (1.f / NN) - mu*mu;
    float g = gamma[tid] * rsqrtf(var + BN_EPS);
    gbL[tid] = g;
    bbL[tid] = beta[tid] - mu*g;
  }
  __syncthreads();

  int row0 = blockIdx.x*64 + (tid >> 6)*16;
  int arow = row0 + (lane & 15); if (arow >= NN) arow = NN - 1;
  int kg = lane >> 4;  // 0..3

  const uint2* A2 = (const uint2*)A;
  f16x4 a[8];
  #pragma unroll
  for (int kt = 0; kt < 8; kt++){
    uint2 v = A2[(size_t)arow*32 + kt*4 + kg];
    int c0 = kt*16 + kg*4;
    float4 g = *(const float4*)&gbL[c0];
    float4 bo = *(const float4*)&bbL[c0];
    float r0 = frelu(bflo(v.x)*g.x + bo.x);
    float r1 = frelu(bfhi(v.x)*g.y + bo.y);
    float r2 = frelu(bflo(v.y)*g.z + bo.z);
    float r3 = frelu(bfhi(v.y)*g.w + bo.w);
    *(float4*)&o1[(size_t)arow*D + c0] = make_float4(r0, r1, r2, r3);  // fused BN+ReLU output
    f16x4 av;
    av[0] = (_Float16)r0; av[1] = (_Float16)r1; av[2] = (_Float16)r2; av[3] = (_Float16)r3;
    a[kt] = av;
  }

  f32x4 acc[8];
  #pragma unroll
  for (int nt = 0; nt < 8; nt++){ acc[nt][0] = 0.f; acc[nt][1] = 0.f; acc[nt][2] = 0.f; acc[nt][3] = 0.f; }

  #pragma unroll
  for (int kt = 0; kt < 8; kt++){
    #pragma unroll
    for (int nt = 0; nt < 8; nt++){
      f16x4 bfr = __builtin_bit_cast(f16x4, Wpk[(nt*8 + kt)*64 + lane]);
      acc[nt] = __builtin_amdgcn_mfma_f32_16x16x16f16(a[kt], bfr, acc[nt], 0, 0, 0);
    }
  }

  int rbase = row0 + kg*4;
  float4 dv = *(const float4*)&dinv[rbase];
  #pragma unroll
  for (int r = 0; r < 4; r++){
    int row = rbase + r;
    if (row < NN){
      float sc = (r == 0) ? dv.x : (r == 1) ? dv.y : (r == 2) ? dv.z : dv.w;
      #pragma unroll
      for (int nt = 0; nt < 8; nt++)
        H[(size_t)row*D + nt*16 + (lane & 15)] = f2bf(acc[nt][r]*sc);
    }
  }
}

// ---------------- aggregate: R6 gather shape + fused BN column sums --------------
__global__ __launch_bounds__(256) void k_agg(const unsigned int* __restrict__ Hp,
                                             const float* __restrict__ dinv,
                                             const int* __restrict__ rowStart,
                                             const int* __restrict__ cnt,
                                             const int* __restrict__ colIdx,
                                             unsigned int* __restrict__ outb,
                                             float* __restrict__ colsumR){
  __shared__ float lsum[128], lsq[128];
  int tid = threadIdx.x;
  if (tid < 128){ lsum[tid] = 0.f; lsq[tid] = 0.f; }
  __syncthreads();

  int lane = tid & 63, wv = tid >> 6;
  float cs0 = 0.f, cs1 = 0.f, cq0 = 0.f, cq1 = 0.f;

  for (int g = blockIdx.x; g < NN/4; g += gridDim.x){
    int node = g*4 + wv;
    int beg = __builtin_amdgcn_readfirstlane(rowStart[node]);
    int n   = __builtin_amdgcn_readfirstlane(cnt[node]);
    int nP  = (n + 8) & ~7;            // (n+1 entries incl. self) padded to x8
    const int* cp = colIdx + beg;

    float2 a0 = make_float2(0.f, 0.f), a1 = a0, a2 = a0, a3 = a0;
    float2 a4 = a0, a5 = a0, a6 = a0, a7 = a0;
    for (int j = 0; j < nP; j += 8){
      int i0 = cp[j  ], i1 = cp[j+1], i2 = cp[j+2], i3 = cp[j+3];
      int i4 = cp[j+4], i5 = cp[j+5], i6 = cp[j+6], i7 = cp[j+7];
      unsigned int v0 = Hp[i0 + lane];
      unsigned int v1 = Hp[i1 + lane];
      unsigned int v2 = Hp[i2 + lane];
      unsigned int v3 = Hp[i3 + lane];
      unsigned int v4 = Hp[i4 + lane];
      unsigned int v5 = Hp[i5 + lane];
      unsigned int v6 = Hp[i6 + lane];
      unsigned int v7 = Hp[i7 + lane];
      a0.x += bflo(v0); a0.y += bfhi(v0);
      a1.x += bflo(v1); a1.y += bfhi(v1);
      a2.x += bflo(v2); a2.y += bfhi(v2);
      a3.x += bflo(v3); a3.y += bfhi(v3);
      a4.x += bflo(v4); a4.y += bfhi(v4);
      a5.x += bflo(v5); a5.y += bfhi(v5);
      a6.x += bflo(v6); a6.y += bfhi(v6);
      a7.x += bflo(v7); a7.y += bfhi(v7);
    }

    float sx = ((a0.x + a1.x) + (a2.x + a3.x)) + ((a4.x + a5.x) + (a6.x + a7.x));
    float sy = ((a0.y + a1.y) + (a2.y + a3.y)) + ((a4.y + a5.y) + (a6.y + a7.y));
    float di = dinv[node];
    unsigned int pk = (unsigned int)f2bf(di*sx) | ((unsigned int)f2bf(di*sy) << 16);
    outb[node*64 + lane] = pk;

    float r0 = bflo(pk), r1 = bfhi(pk);
    cs0 += r0; cq0 += r0*r0;
    cs1 += r1; cq1 += r1*r1;
  }

  atomicAdd(&lsum[lane*2    ], cs0); atomicAdd(&lsq[lane*2    ], cq0);
  atomicAdd(&lsum[lane*2 + 1], cs1); atomicAdd(&lsq[lane*2 + 1], cq1);
  __syncthreads();
  int bank = (blockIdx.x & 7)*256;
  if (tid < 128) atomicAdd(&colsumR[bank + tid], lsum[tid]);
  else if (tid < 256) atomicAdd(&colsumR[bank + tid], lsq[tid - 128]);
}

// ---------------- BN apply + ReLU (layer 2): gb/bb inline, grid-stride -----------
__global__ __launch_bounds__(256) void k_bnapply(const unsigned int* __restrict__ A,
                                                 const float* __restrict__ colsum,
                                                 const float* __restrict__ gamma, const float* __restrict__ beta,
                                                 float* __restrict__ out){
  __shared__ float gbL[128], bbL[128];
  int tid = threadIdx.x;
  if (tid < 128){
    float s = 0.f, q = 0.f;
    #pragma unroll
    for (int k = 0; k < 8; k++){ s += colsum[k*256 + tid]; q += colsum[k*256 + 128 + tid]; }
    float mu = s * (1.f / NN);
    float var = q * (1.f / NN) - mu*mu;
    float g = gamma[tid] * rsqrtf(var + BN_EPS);
    gbL[tid] = g;
    bbL[tid] = beta[tid] - mu*g;
  }
  __syncthreads();

  for (int idx = blockIdx.x*256 + tid; idx < NN*64; idx += gridDim.x*256){
    unsigned int v = A[idx];
    int c2 = idx & 63;
    float2 g = ((const float2*)gbL)[c2];
    float2 b = ((const float2*)bbL)[c2];
    float lo = frelu(bflo(v)*g.x + b.x);
    float hi = frelu(bfhi(v)*g.y + b.y);
    ((float2*)out)[idx] = make_float2(lo, hi);
  }
}

extern "C" void kernel_launch(void* const* d_in, const int* in_sizes, int n_in,
                              void* d_out, int out_size, void* d_ws, size_t ws_size,
                              hipStream_t stream){
  const float* x   = (const float*)d_in[0];
  const int*   ei  = (const int*)d_in[1];   // [2][NE], row0 = src, row1 = dst
  const float* W1  = (const float*)d_in[2];
  const float* g1  = (const float*)d_in[4];
  const float* be1 = (const float*)d_in[5];
  const float* W2  = (const float*)d_in[6];
  const float* g2  = (const float*)d_in[8];
  const float* be2 = (const float*)d_in[9];
  // b1/b2 cancel exactly inside BatchNorm (agg+b - mean(agg+b)) -> skipped.

  float* out = (float*)d_out;
  float* o1 = out;
  float* o2 = out + (size_t)NN*D;

  char* ws = (char*)d_ws;
  int*   cnt         = (int*)(ws + 0);           // 400000 B
  int*   rowStart    = (int*)(ws + 400384);      // 400000 B (padded starts)
  float* dinv        = (float*)(ws + 800768);    // 400000 B
  float* colsumB     = (float*)(ws + 1201152);   // 16384 B (2 regions x 8 banks x 256)
  int*   wgLoc       = (int*)(ws + 1217536);     // 627200 B
  unsigned long long* Wpk1 = (unsigned long long*)(ws + 1844736);  // 32768 B
  unsigned long long* Wpk2 = (unsigned long long*)(ws + 1877504);  // 32768 B
  int*   colIdx      = (int*)(ws + 1910272);     // (NE + 8*NN + 256)*4 = 9601024 B
  unsigned int* binned = (unsigned int*)(ws + 11511296);  // 6.4 MB
  unsigned int* aggb = (unsigned int*)(ws + 17911296);    // 25.6 MB (bf16 agg)
  unsigned short* h  = (unsigned short*)(ws + 43511296);  // 25.6 MB + 256 B zero row
  // total ~69.1 MB of ws

  float* colsum0 = colsumB;          // layer-1 region
  float* colsum1 = colsumB + 2048;   // layer-2 region

  // ---- build: sort+prep fused, then node build (bucket scan fused via wgLoc sums) ----
  k_sortprep<<<NWG_BIN + 3, 256, 0, stream>>>(ei, wgLoc, binned, W1, W2, Wpk1, Wpk2, colsumB, (unsigned int*)h);
  kb_node2  <<<NB, 256, 0, stream>>>(binned, wgLoc, cnt, rowStart, dinv, colIdx);

  // ---- layer 1 ----
  k_gemm1   <<<(NN + 63)/64, 256, 0, stream>>>(x, Wpk1, dinv, h);
  k_agg     <<<AGG_BLOCKS, 256, 0, stream>>>((const unsigned int*)h, dinv, rowStart, cnt, colIdx, aggb, colsum0);

  // ---- layer 2 (gemm computes gb/bb inline, applies BN+ReLU, emits o1) ----
  k_gemm2   <<<(NN + 63)/64, 256, 0, stream>>>(aggb, colsum0, g1, be1, Wpk2, dinv, h, o1);
  k_agg     <<<AGG_BLOCKS, 256, 0, stream>>>((const unsigned int*)h, dinv, rowStart, cnt, colIdx, aggb, colsum1);
  k_bnapply <<<AGG_BLOCKS, 256, 0, stream>>>(aggb, colsum1, g2, be2, o2);
}